// Round 7
// baseline (273.885 us; speedup 1.0000x reference)
//
#include <hip/hip_runtime.h>
#include <hip/hip_bf16.h>

// Problem constants (B,T,H fixed by setup_inputs)
#define B_ 16
#define T_ 8192
#define H_ 256
#define M_ (B_ * T_)   // 131072 rows
#define STRIDE_ 8      // window over [max(0,t-8), t], count = min(t+1, 9)

typedef __bf16 bf16x8 __attribute__((ext_vector_type(8)));
typedef float f32x4 __attribute__((ext_vector_type(4)));

// pack two f32 -> two bf16 (RNE) in one instruction
__device__ __forceinline__ unsigned pk2(float a, float b) {
  unsigned r;
  asm("v_cvt_pk_bf16_f32 %0, %1, %2" : "=v"(r) : "v"(a), "v"(b));
  return r;
}

// ---------------------------------------------------------------------------
// Kernel 1: build Wpk = per-lane 16B B-fragments for direct global->reg loads.
// frag index e = ((it*2+kk)*16 + J)*64 + l  (l = kqc*16+lm)
//   o = J*16+lm (out col), k = it*64 + (kk*4+kqc)*8 + e8  (K index, 0..511)
//   value = bf16( k<256 ? W_lin[o][k] : W_mem[o][k-256] )
// A wave (64 lanes) loading frag (it,kk,J) reads 1KB contiguous. 256 KiB total.
// ---------------------------------------------------------------------------
__global__ __launch_bounds__(256) void wcat_kernel(
    const float* __restrict__ Wl, const float* __restrict__ bl,
    const float* __restrict__ Wm, const float* __restrict__ bm,
    uint4* __restrict__ Wpk, float* __restrict__ bias) {
  const int e = blockIdx.x * 256 + threadIdx.x;  // 0..16383
  const int lm = e & 15;
  const int kqc = (e >> 4) & 3;
  const int J = (e >> 6) & 15;
  const int kk = (e >> 10) & 1;
  const int it = e >> 11;
  const int o = J * 16 + lm;
  const int k0 = it * 64 + (kk * 4 + kqc) * 8;
  float v[8];
#pragma unroll
  for (int e8 = 0; e8 < 8; ++e8) {
    const int k = k0 + e8;
    v[e8] = (k < 256) ? Wl[o * 256 + k] : Wm[o * 256 + (k - 256)];
  }
  uint4 fr;
  fr.x = pk2(v[0], v[1]);
  fr.y = pk2(v[2], v[3]);
  fr.z = pk2(v[4], v[5]);
  fr.w = pk2(v[6], v[7]);
  Wpk[e] = fr;
  if (e < 256) bias[e] = bl[e] + bm[e];
}

// ---------------------------------------------------------------------------
// Kernel 2 (fused): out[M,256] = [x | winmean(x)] @ Wcat^T + bias
// Change vs round 3 (110us, Occupancy 20%, all pipes <25% busy => latency-
// bound at 2 waves/SIMD): OCCUPANCY x2. 512-thread blocks (8 waves), same
// 64-row tile and 64KB LDS -> 2 blocks/CU but 16 waves/CU (4/SIMD). Wave
// tile 64x32 (acc[4][2]) keeps B-frag loads unique per wave (no L2 dup).
// Phase-A per-thread work halves (12-row ring, 4 out rows) and bf16 packing
// uses v_cvt_pk_bf16_f32 (1 inst per pair vs ~7 manual RNE bit-ops).
// grid: 2048 x 512
// (Resubmitted unchanged: rounds 4-6 were infrastructure failures —
//  container/broker at capacity — no counters were ever produced for
//  this version.)
// ---------------------------------------------------------------------------
__global__ __launch_bounds__(512, 4) void fused_kernel(
    const float* __restrict__ x,        // [M, 256] fp32
    const uint4* __restrict__ Wpk,      // 16384 x 16B B-fragments (bf16)
    const float* __restrict__ bias,     // [256]
    float* __restrict__ out) {          // [M, 256] fp32
  __shared__ __align__(16) unsigned short As[64 * 512];  // 64 KB bf16 A-tile
  const int tid = threadIdx.x;
  // XCD-aware swizzle: 2048 % 8 == 0, contiguous 256-tile chunk per XCD.
  const int bid = (blockIdx.x & 7) * 256 + (blockIdx.x >> 3);
  const int m0 = bid << 6;
  const int tb0 = m0 & (T_ - 1);  // token of tile row 0 within its batch
  const int w = tid >> 6;         // wave 0..7
  const int l = tid & 63;
  const int wc = w << 5;          // wave col base (32 cols per wave)
  const int lm = l & 15;
  const int kqc = l >> 4;

  uint4* As16 = (uint4*)As;  // 16B chunks, 64 per row

  // --- B it=0 prefetch (oldest in vm queue; L2-hot) ---
  f32x4 bq0[4], bq1[4];
#pragma unroll
  for (int kk = 0; kk < 2; ++kk)
#pragma unroll
    for (int j = 0; j < 2; ++j)
      bq0[kk * 2 + j] =
          ((const f32x4*)Wpk)[((0 * 2 + kk) * 16 + (w * 2 + j)) * 64 + l];

  // --- Phase A: stage A-tile (x | windowed means), 12-row ring per thread ---
  {
    const int cg = tid & 31;   // col-group: f32 cols cg*8 .. cg*8+7
    const int rg = tid >> 5;   // row-group 0..15: out rows rg*4 .. rg*4+3
    const int c0 = cg << 3;
    f32x4 h[3][2];             // history rows 0..2 of the 12-row window
    f32x4 s0 = (f32x4){0.f, 0.f, 0.f, 0.f};
    f32x4 s1 = (f32x4){0.f, 0.f, 0.f, 0.f};
#pragma unroll
    for (int r = 0; r < 12; ++r) {
      const int lr = (rg << 2) - 8 + r;  // local row (-8 .. 63)
      f32x4 va = (f32x4){0.f, 0.f, 0.f, 0.f};
      f32x4 vb = (f32x4){0.f, 0.f, 0.f, 0.f};
      if (tb0 + lr >= 0) {               // zero before batch start
        const f32x4* xr = (const f32x4*)(x + (size_t)(m0 + lr) * 256 + c0);
        va = xr[0];
        vb = xr[1];
      }
      s0 += va;
      s1 += vb;
      if (r >= 9) { s0 -= h[r - 9][0]; s1 -= h[r - 9][1]; }
      if (r < 3) { h[r][0] = va; h[r][1] = vb; }
      if (r >= 8) {
        const int R = (rg << 2) + (r - 8);  // output local row 0..63
        const int t = tb0 + R;
        const float inv = (t >= STRIDE_)
                              ? (1.f / 9.f)
                              : __builtin_amdgcn_rcpf((float)(t + 1));
        // x-half: logical chunk q = cg (bf16 cols 8cg..8cg+7)
        uint4 xp;
        xp.x = pk2(va.x, va.y); xp.y = pk2(va.z, va.w);
        xp.z = pk2(vb.x, vb.y); xp.w = pk2(vb.z, vb.w);
        As16[R * 64 + (cg ^ (R & 7))] = xp;
        // mean-half: logical chunk q = 32+cg (bf16 cols 256+8cg ..)
        const f32x4 m0v = s0 * inv, m1v = s1 * inv;
        uint4 mp;
        mp.x = pk2(m0v.x, m0v.y); mp.y = pk2(m0v.z, m0v.w);
        mp.z = pk2(m1v.x, m1v.y); mp.w = pk2(m1v.z, m1v.w);
        As16[R * 64 + ((32 + cg) ^ (R & 7))] = mp;
      }
    }
  }
  __syncthreads();  // A-tile complete

  // --- K-loop: 8 iterations of K=64, NO barriers ---
  f32x4 acc[4][2];
#pragma unroll
  for (int i = 0; i < 4; ++i)
#pragma unroll
    for (int j = 0; j < 2; ++j) acc[i][j] = (f32x4){0.f, 0.f, 0.f, 0.f};

#pragma unroll
  for (int it = 0; it < 8; ++it) {
    f32x4* cur = (it & 1) ? bq1 : bq0;
    f32x4* nxt = (it & 1) ? bq0 : bq1;
    if (it < 7) {
#pragma unroll
      for (int kk = 0; kk < 2; ++kk)
#pragma unroll
        for (int j = 0; j < 2; ++j)
          nxt[kk * 2 + j] =
              ((const f32x4*)Wpk)[(((it + 1) * 2 + kk) * 16 + (w * 2 + j)) * 64 + l];
    }
#pragma unroll
    for (int kk = 0; kk < 2; ++kk) {
      const int qa = it * 8 + kk * 4 + kqc;  // 16B chunk index in A row
      bf16x8 a[4];
#pragma unroll
      for (int i = 0; i < 4; ++i) {
        const int R = (i << 4) + lm;
        a[i] = ((const bf16x8*)As)[R * 64 + (qa ^ (R & 7))];
      }
#pragma unroll
      for (int i = 0; i < 4; ++i)
#pragma unroll
        for (int j = 0; j < 2; ++j)
          acc[i][j] = __builtin_amdgcn_mfma_f32_16x16x32_bf16(
              a[i], __builtin_bit_cast(bf16x8, cur[kk * 2 + j]), acc[i][j],
              0, 0, 0);
    }
  }

  // --- Epilogue: acc -> LDS (f32, reuse As) -> coalesced full-row stores ---
  __syncthreads();  // all ds_reads of A-tile done before overwrite
  float* Os = (float*)As;  // [64][256] f32, chunk-swizzled (16B chunks)
  const int r0 = kqc << 2;
#pragma unroll
  for (int j = 0; j < 2; ++j) {
    const int o = wc + (j << 4) + lm;
    const float bs = bias[o];
    const int qo = o >> 2, so = o & 3;
#pragma unroll
    for (int i = 0; i < 4; ++i) {
#pragma unroll
      for (int r = 0; r < 4; ++r) {
        const int row = (i << 4) + r0 + r;
        Os[row * 256 + ((qo ^ (row & 7)) << 2) + so] = acc[i][j][r] + bs;
      }
    }
  }
  __syncthreads();
#pragma unroll
  for (int k = 0; k < 8; ++k) {
    const int row = (w << 3) + k;  // wave streams a full 1KB row
    const f32x4 vv = ((const f32x4*)Os)[row * 64 + (l ^ (row & 7))];
    ((f32x4*)(out + (size_t)(m0 + row) * 256))[l] = vv;
  }
}

// ---------------------------------------------------------------------------
extern "C" void kernel_launch(void* const* d_in, const int* in_sizes, int n_in,
                              void* d_out, int out_size, void* d_ws, size_t ws_size,
                              hipStream_t stream) {
  const float* x  = (const float*)d_in[0];
  const float* Wl = (const float*)d_in[1];
  const float* bl = (const float*)d_in[2];
  const float* Wm = (const float*)d_in[3];
  const float* bm = (const float*)d_in[4];
  float* out = (float*)d_out;

  // workspace: Wpk 16384 x 16B (256 KiB) + bias 256 f32 (1 KiB)
  char* ws = (char*)d_ws;
  uint4* Wpk = (uint4*)ws;
  float* bias = (float*)(ws + (size_t)16384 * 16);

  wcat_kernel<<<64, 256, 0, stream>>>(Wl, bl, Wm, bm, Wpk, bias);
  fused_kernel<<<2048, 512, 0, stream>>>(x, Wpk, bias, out);
}